// Round 19
// baseline (2233.444 us; speedup 1.0000x reference)
//
#include <hip/hip_runtime.h>

#define NBATCH   131072
#define FDIM     16
#define NLAYER   8
#define HDIM     256
#define PCOLS    208      // 8 fslots x 26 (25 used + 1 pad)
#define PSTRIDE  212      // p stride (u16): 424B rows, 8B-aligned
#define TSTRIDE  264      // t stride (u16): 528B rows, 16B-aligned
#define MTILE    64
#define NTHREADS 256
#define TBUF     (MTILE*TSTRIDE)   // 16896 u16 = 33792 B

typedef unsigned short u16;
typedef __attribute__((ext_vector_type(8))) __bf16 bf16x8;
typedef __attribute__((ext_vector_type(8))) u16    u16x8;
typedef __attribute__((ext_vector_type(4))) u16    u16x4;
typedef __attribute__((ext_vector_type(2))) u16    u16x2;
typedef __attribute__((ext_vector_type(4))) float  f32x4;

// ws layout (bytes)
#define WRP_OFF  0u            // 8*4*8*4*256*8 bf16 = 4,194,304 B
#define W0P_OFF  4194304u      // 8*4*256*8 bf16    =   131,072 B
#define WFP_OFF  4325376u      // 8*8*4*208*8 bf16  =   851,968 B
#define BFP_OFF  5177344u      // 8*208 f32         =     6,656 B (last slot = sum log|scale|)

__device__ __forceinline__ u16 f2bf(float f){
  __bf16 h = (__bf16)f;
  return __builtin_bit_cast(u16, h);
}
__device__ __forceinline__ float bf2f(u16 b){
  unsigned u = ((unsigned)b) << 16;
  return __builtin_bit_cast(float, u);
}
__device__ __forceinline__ f32x4 mfma16(bf16x8 a, bf16x8 b, f32x4 c){
  return __builtin_amdgcn_mfma_f32_16x16x32_bf16(a, b, c, 0, 0, 0);
}

// ---------------- weight pre-pack kernels ----------------
__global__ void pack_wr_k(const float* __restrict__ Wr, u16* __restrict__ Wrp){
  int idx = blockIdx.x*256 + threadIdx.x;            // 262144
  int n = idx & 255, g = (idx>>8)&3, ks = (idx>>10)&7, m = (idx>>13)&3, l = idx>>15;
  const float* src = Wr + (((size_t)(l*4+m)*HDIM + (ks*32+g*8))*HDIM + n);
  u16x8 v;
  #pragma unroll
  for (int j=0;j<8;++j) v[j] = f2bf(src[(size_t)j*HDIM]);
  *(u16x8*)(Wrp + (size_t)idx*8) = v;
}
__global__ void pack_w0_k(const float* __restrict__ W0, u16* __restrict__ W0p){
  int idx = blockIdx.x*256 + threadIdx.x;            // 8192
  int n = idx&255, g=(idx>>8)&3, l=idx>>10;
  u16x8 v;
  #pragma unroll
  for (int j=0;j<8;++j){ int k=g*8+j; v[j] = (k<FDIM) ? f2bf(W0[(l*FDIM+k)*HDIM+n]) : (u16)0; }
  *(u16x8*)(W0p + (size_t)idx*8) = v;
}
// Wfp: gathered 26-stride cols: nc -> fslot=nc/26, k=nc%26 (k<25 valid), f=2*fslot+(l&1)
__global__ void pack_wf_k(const float* __restrict__ Wf, u16* __restrict__ Wfp){
  int idx = blockIdx.x*256 + threadIdx.x;            // 53248
  int nc = idx % PCOLS; int t = idx / PCOLS;
  int g = t&3, ks=(t>>2)&7, l=t>>5;
  int fs = nc/26, kk = nc%26;
  u16x8 v = {0,0,0,0,0,0,0,0};
  if (kk < 25){
    int f = 2*fs + (l&1);
    int col = f*25 + kk;
    #pragma unroll
    for (int j=0;j<8;++j){ int k=ks*32+g*8+j; v[j]=f2bf(Wf[((size_t)l*HDIM+k)*400+col]); }
  }
  *(u16x8*)(Wfp + (size_t)idx*8) = v;
}
__global__ void pack_bf_k(const float* __restrict__ bf, const float* __restrict__ scales,
                          float* __restrict__ bfp){
  int idx = blockIdx.x*256 + threadIdx.x;
  if (idx >= NLAYER*PCOLS) return;
  if (idx == NLAYER*PCOLS-1){                        // pad slot reused: sum log|scale|
    float s = 0.f;
    for (int i=0;i<NLAYER*FDIM;++i) s += __logf(fabsf(scales[i]));
    bfp[idx] = s;
    return;
  }
  int nc = idx % PCOLS, l = idx / PCOLS;
  int fs = nc/26, kk = nc%26;
  float v = 0.f;
  if (kk < 25){ int f=2*fs+(l&1); v = bf[l*400 + f*25 + kk]; }
  bfp[idx] = v;
}

// ---------------- fused flow kernel ----------------
// MTILE=64, 4 waves x (64 rows x 64 cols) => 1:4 weight:MFMA (R17 lesson).
// ONE f32 accumulator acc[16]; trunk h parked as bf16 in 32 VGPRs (R17-validated).
// Single-buffer t => 38.9KB LDS; NO min-waves clamp (clamped builds corrupt R5/R6/R16).
__global__ __launch_bounds__(NTHREADS)
void flow_kernel(const float* __restrict__ xg,
                 const float* __restrict__ b0g,
                 const float* __restrict__ brg,
                 const float* __restrict__ scg,
                 const float* __restrict__ shg,
                 const int*   __restrict__ pmg,
                 const u16*   __restrict__ w0p,
                 const u16*   __restrict__ wrp,
                 const u16*   __restrict__ wfp,
                 const float* __restrict__ bfp,
                 float* __restrict__ outg)
{
  __shared__ u16   t_lds[TBUF];            // 33792 B; aliased by p after GEMM3
  __shared__ float x_lds[MTILE*FDIM];      // 4096 B
  __shared__ float pe_lds[HDIM];           // 1024 B
  u16* p_lds = t_lds;

  const int tid  = threadIdx.x;
  const int wn   = tid >> 6;      // wave = col quarter (0..3)
  const int lane = tid & 63;
  const int lr = lane & 15;
  const int lg = lane >> 4;
  const int rowg0 = blockIdx.x * MTILE;
  const int srow = tid >> 2;      // 4 threads/row (rows wave-local)
  const int sq   = tid & 3;

  if (tid < HDIM) pe_lds[tid] = sinf(6.283185307179586f * (float)tid / 256.0f);

  { // load x tile (coalesced float4)
    float4 v = *(const float4*)(xg + (size_t)(rowg0+srow)*FDIM + sq*4);
    *(float4*)(x_lds + srow*FDIM + sq*4) = v;
  }
  float ld_acc = 0.f;
  __syncthreads();                                   // B0

  const bf16x8* wrp8 = (const bf16x8*)wrp;
  const bf16x8* w0p8 = (const bf16x8*)w0p;
  const bf16x8* wfp8 = (const bf16x8*)wfp;

  f32x4 acc[16];    // acc[mi*4+ni][r] = val[row mi*16+lr][col wn*64+ni*16+lg*4+r]
  u16x4 hreg[16];   // trunk h parked as bf16 (32 VGPRs)

  auto h_save = [&](){
    #pragma unroll
    for (int f=0; f<16; ++f){
      #pragma unroll
      for (int r=0;r<4;++r) hreg[f][r] = f2bf(acc[f][r]);
    }
  };

  // stage relu(acc [+pe]) as bf16 into t
  auto stage_acc = [&](bool use_pe){
    #pragma unroll
    for (int mi=0; mi<4; ++mi){
      u16* dst = t_lds + (mi*16 + lr)*TSTRIDE;
      #pragma unroll
      for (int ni=0; ni<4; ++ni){
        const int col = wn*64 + ni*16 + lg*4;
        f32x4 v = acc[mi*4+ni];
        if (use_pe){
          f32x4 pv = *(const f32x4*)(pe_lds + col);
          #pragma unroll
          for (int r=0;r<4;++r) v[r] += pv[r];
        }
        u16x4 pk;
        #pragma unroll
        for (int r=0;r<4;++r) pk[r] = f2bf(fmaxf(v[r], 0.f));
        *(u16x4*)(dst + col) = pk;
      }
    }
  };

  // acc = C-init + t @ W ; C-init = br [+ hreg trunk]  (R17-validated in-place form)
  auto mm = [&](const bf16x8* wb8, const float* brp, bool add_h){
    #pragma unroll
    for (int ni=0; ni<4; ++ni){
      f32x4 bv = *(const f32x4*)(brp + wn*64 + ni*16 + lg*4);
      #pragma unroll
      for (int mi=0; mi<4; ++mi){
        const int f = mi*4+ni;
        if (add_h){
          #pragma unroll
          for (int r=0;r<4;++r) acc[f][r] = bf2f(hreg[f][r]) + bv[r];
        } else {
          acc[f] = bv;
        }
      }
    }
    const int bofs  = lg*256 + wn*64 + lr;
    const int abase = lr*TSTRIDE;
    #pragma unroll
    for (int ks=0; ks<8; ++ks){
      bf16x8 a[4];
      #pragma unroll
      for (int mi=0; mi<4; ++mi)
        a[mi] = *(const bf16x8*)(t_lds + abase + mi*16*TSTRIDE + ks*32 + lg*8);
      #pragma unroll
      for (int ni=0; ni<4; ++ni){
        bf16x8 w = wb8[ks*1024 + bofs + ni*16];
        #pragma unroll
        for (int mi=0; mi<4; ++mi)
          acc[mi*4+ni] = mfma16(w, a[mi], acc[mi*4+ni]);
      }
    }
  };

  for (int li=0; li<NLAYER; ++li){
    // ---- permute + affine (row-local => intra-wave, no barrier) ----
    {
      float tv[4];
      #pragma unroll
      for (int j=0;j<4;++j){
        const int f  = sq*4 + j;
        const int pf = pmg[li*FDIM + f];
        const float sc = scg[li*FDIM + f];
        tv[j] = x_lds[srow*FDIM + pf]*sc + shg[li*FDIM + f];
      }
      #pragma unroll
      for (int j=0;j<4;++j) x_lds[srow*FDIM + sq*4 + j] = tv[j];
    }

    // ---- stage xm (masked, K padded to 32): t free since last layer's B14 ----
    {
      u16x8 pk;
      #pragma unroll
      for (int j=0;j<8;++j){
        const int f = sq*8 + j;
        float v = 0.f;
        if (f < FDIM && ((f & 1) != (li & 1))) v = x_lds[srow*FDIM + f];
        pk[j] = f2bf(v);
      }
      *(u16x8*)(t_lds + srow*TSTRIDE + sq*8) = pk;
    }
    __syncthreads();                                 // B1: xm visible

    // ---- GEMM1: acc = xm @ W0 + b0 ----
    {
      #pragma unroll
      for (int ni=0; ni<4; ++ni){
        f32x4 bv = *(const f32x4*)(b0g + li*HDIM + wn*64 + ni*16 + lg*4);
        #pragma unroll
        for (int mi=0; mi<4; ++mi) acc[mi*4+ni] = bv;
      }
      #pragma unroll
      for (int mi=0; mi<4; ++mi){
        bf16x8 a = *(const bf16x8*)(t_lds + (mi*16 + lr)*TSTRIDE + lg*8);
        #pragma unroll
        for (int ni=0; ni<4; ++ni){
          bf16x8 w = w0p8[li*1024 + lg*256 + wn*64 + ni*16 + lr];
          acc[mi*4+ni] = mfma16(w, a, acc[mi*4+ni]);
        }
      }
    }
    __syncthreads();                                 // B2: G1 t-reads done
    h_save();                                        // trunk h -> hreg (bf16)
    stage_acc(true);                                 // relu(h+pe) -> t
    __syncthreads();                                 // B3

    // ---- residual block 1 ----
    mm(wrp8 + (size_t)(li*4 + 0)*8192, brg + (li*4 + 0)*HDIM, false);  // y1
    __syncthreads();                                 // B4: mm1 t-reads done
    stage_acc(true);                                 // relu(y1+pe) -> t
    __syncthreads();                                 // B5
    mm(wrp8 + (size_t)(li*4 + 1)*8192, brg + (li*4 + 1)*HDIM, true);   // h = h + (y2-path)
    __syncthreads();                                 // B6: mm2 t-reads done
    h_save();
    stage_acc(true);                                 // relu(h+pe) -> t
    __syncthreads();                                 // B7

    // ---- residual block 2 ----
    mm(wrp8 + (size_t)(li*4 + 2)*8192, brg + (li*4 + 2)*HDIM, false);  // y3
    __syncthreads();                                 // B8
    stage_acc(true);                                 // relu(y3+pe) -> t
    __syncthreads();                                 // B9
    mm(wrp8 + (size_t)(li*4 + 3)*8192, brg + (li*4 + 3)*HDIM, true);   // h final
    __syncthreads();                                 // B10
    stage_acc(false);                                // relu(h) -> t (G3 input)
    __syncthreads();                                 // B11

    // ---- GEMM3: p = relu(h) @ Wf_gathered + bf ----
    {
      const int NFRAG = (wn==0) ? 4 : 3;   // 13 N-frags split 4/3/3/3
      f32x4 pacc[16];
      #pragma unroll
      for (int i=0;i<16;++i){ f32x4 z={0.f,0.f,0.f,0.f}; pacc[i]=z; }
      const int abase = lr*TSTRIDE;
      #pragma unroll
      for (int ks=0; ks<8; ++ks){
        bf16x8 a[4];
        #pragma unroll
        for (int mi=0;mi<4;++mi)
          a[mi] = *(const bf16x8*)(t_lds + abase + mi*16*TSTRIDE + ks*32 + lg*8);
        #pragma unroll
        for (int t=0;t<4;++t){
          if (t < NFRAG){
            const int nf = wn + 4*t;
            bf16x8 w = wfp8[li*6656 + ks*832 + lg*208 + nf*16 + lr];
            #pragma unroll
            for (int mi=0;mi<4;++mi)
              pacc[mi*4+t] = mfma16(w, a[mi], pacc[mi*4+t]);
          }
        }
      }
      __syncthreads();                               // B12: G3 t-reads done (p aliases t)
      #pragma unroll
      for (int t=0;t<4;++t){
        if (t < NFRAG){
          const int nf = wn + 4*t;
          const int col = nf*16 + lg*4;
          f32x4 bv = *(const f32x4*)(bfp + li*PCOLS + col);
          #pragma unroll
          for (int mi=0;mi<4;++mi){
            const int prow = mi*16 + lr;
            u16x4 pk;
            #pragma unroll
            for (int r=0;r<4;++r) pk[r] = f2bf(pacc[mi*4+t][r] + bv[r]);
            *(u16x4*)(p_lds + prow*PSTRIDE + col) = pk;
          }
        }
      }
    }
    __syncthreads();                                 // B13: p visible

    // ---- RQ spline on the 8 transformed features ----
    {
      #pragma unroll
      for (int e=0; e<2; ++e){
        const int fslot = sq*2 + e;
        const int ft = fslot*2 + (li & 1);
        const float xv = x_lds[srow*FDIM + ft];
        const u16* pp = p_lds + srow*PSTRIDE + fslot*26;
        float uw[8], uh[8], us[9];
        #pragma unroll
        for (int k2=0;k2<4;++k2){ u16x2 v = *(const u16x2*)(pp + 2*k2);      uw[2*k2]=bf2f(v[0]); uw[2*k2+1]=bf2f(v[1]); }
        #pragma unroll
        for (int k2=0;k2<4;++k2){ u16x2 v = *(const u16x2*)(pp + 8 + 2*k2);  uh[2*k2]=bf2f(v[0]); uh[2*k2+1]=bf2f(v[1]); }
        #pragma unroll
        for (int k2=0;k2<4;++k2){ u16x2 v = *(const u16x2*)(pp + 16 + 2*k2); us[2*k2]=bf2f(v[0]); us[2*k2+1]=bf2f(v[1]); }
        us[8] = bf2f(pp[24]);
        float mw = uw[0], mh = uh[0];
        #pragma unroll
        for (int k=1;k<8;++k){ mw=fmaxf(mw,uw[k]); mh=fmaxf(mh,uh[k]); }
        float sw=0.f, sh=0.f, bw[8], bh[8];
        #pragma unroll
        for (int k=0;k<8;++k){ bw[k]=__expf(uw[k]-mw); sw+=bw[k]; bh[k]=__expf(uh[k]-mh); sh+=bh[k]; }
        const float wscl = 9.9992f / sw;
        const float hscl = 9.9992f / sh;
        #pragma unroll
        for (int k=0;k<8;++k){ bw[k]=bw[k]*wscl + 1e-4f; bh[k]=bh[k]*hscl + 1e-4f; }
        float dv[9];
        #pragma unroll
        for (int k=0;k<9;++k){
          const float v = us[k] + 0.5411667f;          // log(expm1(1-1e-4))
          const float spv = (v > 15.f) ? v : __logf(1.f + __expf(v));
          dv[k] = spv + 1e-4f;
        }
        const float xr = xv + 5.f;
        float cw=0.f, ch=0.f;
        float x0=0.f, y0=0.f, x1=0.f, y1=0.f, d0=0.f, d1=0.f;
        #pragma unroll
        for (int k=0;k<8;++k){
          const float nw = cw + bw[k];
          const float nh = ch + bh[k];
          const bool take = (k==0) || (xr >= cw);
          if (take){ x0=cw; y0=ch; x1=nw; y1=nh; d0=dv[k]; d1=dv[k+1]; }
          cw = nw; ch = nh;
        }
        const float dx = x1 - x0;
        const float s  = (y1 - y0) / dx;
        float z = (xr - x0) / dx;
        z = fminf(fmaxf(z, 0.f), 1.f);
        const float zm  = 1.f - z;
        const float den = s + (d1 + d0 - 2.f*s)*z*zm;
        const float yout = (y0 - 5.f) + (y1 - y0)*(s*z*z + d0*z*zm)/den;
        const float nrm  = d1*z*z + 2.f*s*z*zm + d0*zm*zm;
        const float ld   = __logf(s*s*nrm/(den*den));
        const bool inside = (xv >= -5.f) && (xv <= 5.f);
        x_lds[srow*FDIM + ft] = inside ? yout : xv;   // own-row write (intra-wave)
        ld_acc += inside ? ld : 0.f;
      }
    }
    __syncthreads();                                 // B14: p-reads done; t free for next xm
  }

  // ---- base log-prob + reduce 4 threads/row ----
  {
    float s2 = 0.f;
    #pragma unroll
    for (int j=0;j<4;++j){
      const float xv = x_lds[srow*FDIM + sq*4 + j];
      s2 += xv*xv;
    }
    float tot = ld_acc - 0.5f*s2;
    tot += __shfl_xor(tot, 1);
    tot += __shfl_xor(tot, 2);
    if (sq == 0){
      const float sumlogsc = bfp[NLAYER*PCOLS - 1];
      outg[rowg0 + srow] = tot + sumlogsc - 14.70301653127476f;  // 0.5*16*log(2*pi)
    }
  }
}

extern "C" void kernel_launch(void* const* d_in, const int* in_sizes, int n_in,
                              void* d_out, int out_size, void* d_ws, size_t ws_size,
                              hipStream_t stream) {
  (void)in_sizes; (void)n_in; (void)out_size; (void)ws_size;
  const float* x  = (const float*)d_in[0];
  const float* W0 = (const float*)d_in[1];
  const float* b0 = (const float*)d_in[2];
  const float* Wr = (const float*)d_in[3];
  const float* br = (const float*)d_in[4];
  const float* Wf = (const float*)d_in[5];
  const float* bf = (const float*)d_in[6];
  const float* sc = (const float*)d_in[7];
  const float* sh = (const float*)d_in[8];
  const int*   pm = (const int*)d_in[9];

  char* ws = (char*)d_ws;
  u16*   Wrp = (u16*)(ws + WRP_OFF);
  u16*   W0p = (u16*)(ws + W0P_OFF);
  u16*   Wfp = (u16*)(ws + WFP_OFF);
  float* bfp = (float*)(ws + BFP_OFF);

  pack_wr_k<<<1024, 256, 0, stream>>>(Wr, Wrp);
  pack_w0_k<<<32,   256, 0, stream>>>(W0, W0p);
  pack_wf_k<<<208,  256, 0, stream>>>(Wf, Wfp);
  pack_bf_k<<<7,    256, 0, stream>>>(bf, sc, bfp);

  flow_kernel<<<NBATCH/MTILE, NTHREADS, 0, stream>>>(
      x, b0, br, sc, sh, pm, W0p, Wrp, Wfp, bfp, (float*)d_out);
}

// Round 20
// 1005.883 us; speedup vs baseline: 2.2204x; 2.2204x over previous
//
#include <hip/hip_runtime.h>

#define NBATCH   131072
#define FDIM     16
#define NLAYER   8
#define HDIM     256
#define PCOLS    208      // 8 fslots x 26 (25 used + 1 pad)
#define PSTRIDE  212      // p stride (u16): 424B rows, 8B-aligned, 106 dwords (~2-way banks)
#define TSTRIDE  264      // t stride (u16): 528B rows, 16B-aligned
#define MTILE    64
#define NTHREADS 256
#define TBUF     (MTILE*TSTRIDE)   // u16 per t buffer (16896)

typedef unsigned short u16;
typedef __attribute__((ext_vector_type(8))) __bf16 bf16x8;
typedef __attribute__((ext_vector_type(8))) u16    u16x8;
typedef __attribute__((ext_vector_type(4))) u16    u16x4;
typedef __attribute__((ext_vector_type(2))) u16    u16x2;
typedef __attribute__((ext_vector_type(4))) float  f32x4;

// ws layout (bytes)
#define WRP_OFF  0u            // 8*4*8*4*256*8 bf16 = 4,194,304 B
#define W0P_OFF  4194304u      // 8*4*256*8 bf16    =   131,072 B
#define WFP_OFF  4325376u      // 8*8*4*208*8 bf16  =   851,968 B
#define BFP_OFF  5177344u      // 8*208 f32         =     6,656 B (last slot = sum log|scale|)

__device__ __forceinline__ u16 f2bf(float f){
  __bf16 h = (__bf16)f;
  return __builtin_bit_cast(u16, h);
}
__device__ __forceinline__ float bf2f(u16 b){
  unsigned u = ((unsigned)b) << 16;
  return __builtin_bit_cast(float, u);
}
__device__ __forceinline__ f32x4 mfma16(bf16x8 a, bf16x8 b, f32x4 c){
  return __builtin_amdgcn_mfma_f32_16x16x32_bf16(a, b, c, 0, 0, 0);
}

// ---------------- weight pre-pack kernels ----------------
__global__ void pack_wr_k(const float* __restrict__ Wr, u16* __restrict__ Wrp){
  int idx = blockIdx.x*256 + threadIdx.x;            // 262144
  int n = idx & 255, g = (idx>>8)&3, ks = (idx>>10)&7, m = (idx>>13)&3, l = idx>>15;
  const float* src = Wr + (((size_t)(l*4+m)*HDIM + (ks*32+g*8))*HDIM + n);
  u16x8 v;
  #pragma unroll
  for (int j=0;j<8;++j) v[j] = f2bf(src[(size_t)j*HDIM]);
  *(u16x8*)(Wrp + (size_t)idx*8) = v;
}
__global__ void pack_w0_k(const float* __restrict__ W0, u16* __restrict__ W0p){
  int idx = blockIdx.x*256 + threadIdx.x;            // 8192
  int n = idx&255, g=(idx>>8)&3, l=idx>>10;
  u16x8 v;
  #pragma unroll
  for (int j=0;j<8;++j){ int k=g*8+j; v[j] = (k<FDIM) ? f2bf(W0[(l*FDIM+k)*HDIM+n]) : (u16)0; }
  *(u16x8*)(W0p + (size_t)idx*8) = v;
}
// Wfp: gathered 26-stride cols: nc -> fslot=nc/26, k=nc%26 (k<25 valid), f=2*fslot+(l&1)
__global__ void pack_wf_k(const float* __restrict__ Wf, u16* __restrict__ Wfp){
  int idx = blockIdx.x*256 + threadIdx.x;            // 53248
  int nc = idx % PCOLS; int t = idx / PCOLS;
  int g = t&3, ks=(t>>2)&7, l=t>>5;
  int fs = nc/26, kk = nc%26;
  u16x8 v = {0,0,0,0,0,0,0,0};
  if (kk < 25){
    int f = 2*fs + (l&1);
    int col = f*25 + kk;
    #pragma unroll
    for (int j=0;j<8;++j){ int k=ks*32+g*8+j; v[j]=f2bf(Wf[((size_t)l*HDIM+k)*400+col]); }
  }
  *(u16x8*)(Wfp + (size_t)idx*8) = v;
}
__global__ void pack_bf_k(const float* __restrict__ bf, const float* __restrict__ scales,
                          float* __restrict__ bfp){
  int idx = blockIdx.x*256 + threadIdx.x;
  if (idx >= NLAYER*PCOLS) return;
  if (idx == NLAYER*PCOLS-1){                        // pad slot reused: sum log|scale|
    float s = 0.f;
    for (int i=0;i<NLAYER*FDIM;++i) s += __logf(fabsf(scales[i]));
    bfp[idx] = s;
    return;
  }
  int nc = idx % PCOLS, l = idx / PCOLS;
  int fs = nc/26, kk = nc%26;
  float v = 0.f;
  if (kk < 25){ int f=2*fs+(l&1); v = bf[l*400 + f*25 + kk]; }
  bfp[idx] = v;
}

// ---------------- fused flow kernel ----------------
// R11 structure (best: 1006us) + s_setprio around MFMA clusters (T5).
// NO min-waves clamp (clamped builds corrupt: R5/R6/R16).
__global__ __launch_bounds__(NTHREADS, 2)
void flow_kernel(const float* __restrict__ xg,
                 const float* __restrict__ b0g,
                 const float* __restrict__ brg,
                 const float* __restrict__ scg,
                 const float* __restrict__ shg,
                 const int*   __restrict__ pmg,
                 const u16*   __restrict__ w0p,
                 const u16*   __restrict__ wrp,
                 const u16*   __restrict__ wfp,
                 const float* __restrict__ bfp,
                 float* __restrict__ outg)
{
  __shared__ u16   t_lds[2*TBUF];          // 67584 B double-buffered; p aliases one buf
  __shared__ float x_lds[MTILE*FDIM];      // 4096 B
  __shared__ float pe_lds[HDIM];           // 1024 B

  const int tid  = threadIdx.x;
  const int wn   = tid >> 6;      // wave = col quarter (0..3)
  const int lane = tid & 63;
  const int lr = lane & 15;
  const int lg = lane >> 4;
  const int rowg0 = blockIdx.x * MTILE;
  const int srow = tid >> 2;      // per-row worker: 4 threads/row (rows are wave-local)
  const int sq   = tid & 3;

  if (tid < HDIM) pe_lds[tid] = sinf(6.283185307179586f * (float)tid / 256.0f);

  { // load x tile (coalesced float4) — own-wave rows only
    float4 v = *(const float4*)(xg + (size_t)(rowg0+srow)*FDIM + sq*4);
    *(float4*)(x_lds + srow*FDIM + sq*4) = v;
  }
  float ld_acc = 0.f;
  __syncthreads();

  const bf16x8* wrp8 = (const bf16x8*)wrp;
  const bf16x8* w0p8 = (const bf16x8*)w0p;
  const bf16x8* wfp8 = (const bf16x8*)wfp;

  f32x4 h[16];

  // acc[mi*4+ni][r] = val[row mi*16+lr][col wn*64+ni*16+lg*4+r]
  auto stage_frags = [&](u16* tbase, const f32x4* src, bool use_pe){
    #pragma unroll
    for (int mi=0; mi<4; ++mi){
      u16* dst = tbase + (mi*16 + lr)*TSTRIDE;
      #pragma unroll
      for (int ni=0; ni<4; ++ni){
        const int col = wn*64 + ni*16 + lg*4;
        f32x4 v = src[mi*4+ni];
        if (use_pe){
          f32x4 pv = *(const f32x4*)(pe_lds + col);
          #pragma unroll
          for (int r=0;r<4;++r) v[r] += pv[r];
        }
        u16x4 pk;
        #pragma unroll
        for (int r=0;r<4;++r) pk[r] = f2bf(fmaxf(v[r], 0.f));
        *(u16x4*)(dst + col) = pk;
      }
    }
  };

  // acc = (accum ? acc : 0) + t @ W + br    (weights as A-operand)
  auto mm_hidden = [&](const u16* tbase, f32x4* acc, const bf16x8* wb8,
                       const float* brp, bool accum){
    f32x4 res[16];
    #pragma unroll
    for (int ni=0; ni<4; ++ni){
      f32x4 bv = *(const f32x4*)(brp + wn*64 + ni*16 + lg*4);
      #pragma unroll
      for (int mi=0; mi<4; ++mi){
        f32x4 r0;
        #pragma unroll
        for (int r=0;r<4;++r) r0[r] = (accum ? acc[mi*4+ni][r] : 0.f) + bv[r];
        res[mi*4+ni] = r0;
      }
    }
    const int bofs  = lg*256 + wn*64 + lr;
    const int abase = lr*TSTRIDE;
    #pragma unroll
    for (int ks=0; ks<8; ++ks){
      bf16x8 w[4], a[4];
      #pragma unroll
      for (int ni=0; ni<4; ++ni)
        w[ni] = wb8[ks*1024 + bofs + ni*16];
      #pragma unroll
      for (int mi=0; mi<4; ++mi)
        a[mi] = *(const bf16x8*)(tbase + abase + mi*16*TSTRIDE + ks*32 + lg*8);
      __builtin_amdgcn_s_setprio(1);
      #pragma unroll
      for (int mi=0; mi<4; ++mi)
        #pragma unroll
        for (int ni=0; ni<4; ++ni)
          res[mi*4+ni] = mfma16(w[ni], a[mi], res[mi*4+ni]);
      __builtin_amdgcn_s_setprio(0);
    }
    #pragma unroll
    for (int i=0;i<16;++i) acc[i] = res[i];
  };

  int tb = 0;   // xm/p buffer for this layer; stages alternate tb^1, tb, ...

  for (int li=0; li<NLAYER; ++li){
    u16* buf0 = t_lds + tb*TBUF;        // xm, stages 2&4, p
    u16* buf1 = t_lds + (tb^1)*TBUF;    // stages 1&3, G3 operand

    // ---- permute + affine (row-local => intra-wave, no barrier) ----
    {
      float tv[4];
      #pragma unroll
      for (int j=0;j<4;++j){
        const int f  = sq*4 + j;
        const int pf = pmg[li*FDIM + f];
        const float sc = scg[li*FDIM + f];
        tv[j] = x_lds[srow*FDIM + pf]*sc + shg[li*FDIM + f];
      }
      #pragma unroll
      for (int j=0;j<4;++j) x_lds[srow*FDIM + sq*4 + j] = tv[j];
    }

    // ---- stage xm (masked x, K padded to 32) into buf0 ----
    {
      u16x8 pk;
      #pragma unroll
      for (int j=0;j<8;++j){
        const int f = sq*8 + j;
        float v = 0.f;
        if (f < FDIM && ((f & 1) != (li & 1))) v = x_lds[srow*FDIM + f];
        pk[j] = f2bf(v);
      }
      *(u16x8*)(buf0 + srow*TSTRIDE + sq*8) = pk;
    }
    __syncthreads();                                   // B1

    // ---- GEMM1: h = xm @ W0 + b0 (reads buf0) ----
    {
      bf16x8 w[4];
      #pragma unroll
      for (int ni=0; ni<4; ++ni)
        w[ni] = w0p8[li*1024 + lg*256 + wn*64 + ni*16 + lr];
      #pragma unroll
      for (int mi=0; mi<4; ++mi){
        bf16x8 a = *(const bf16x8*)(buf0 + (mi*16 + lr)*TSTRIDE + lg*8);
        #pragma unroll
        for (int ni=0; ni<4; ++ni){
          f32x4 z = {0.f,0.f,0.f,0.f};
          h[mi*4+ni] = mfma16(w[ni], a, z);
        }
      }
      #pragma unroll
      for (int ni=0; ni<4; ++ni){
        f32x4 bv = *(const f32x4*)(b0g + li*HDIM + wn*64 + ni*16 + lg*4);
        #pragma unroll
        for (int mi=0; mi<4; ++mi){
          #pragma unroll
          for (int r=0;r<4;++r) h[mi*4+ni][r] += bv[r];
        }
      }
    }

    // ---- 2 residual blocks (4 hidden matmuls), ping-pong buffers ----
    f32x4 y[16];
    stage_frags(buf1, h, true);
    __syncthreads();                                   // B2
    mm_hidden(buf1, y, wrp8 + (size_t)(li*4 + 0)*8192, brg + (li*4 + 0)*HDIM, false);
    stage_frags(buf0, y, true);
    __syncthreads();                                   // B3
    mm_hidden(buf0, h, wrp8 + (size_t)(li*4 + 1)*8192, brg + (li*4 + 1)*HDIM, true);
    stage_frags(buf1, h, true);
    __syncthreads();                                   // B4
    mm_hidden(buf1, y, wrp8 + (size_t)(li*4 + 2)*8192, brg + (li*4 + 2)*HDIM, false);
    stage_frags(buf0, y, true);
    __syncthreads();                                   // B5
    mm_hidden(buf0, h, wrp8 + (size_t)(li*4 + 3)*8192, brg + (li*4 + 3)*HDIM, true);

    // ---- GEMM3: p = relu(h) @ Wf_gathered + bf (operand in buf1, p into buf0) ----
    stage_frags(buf1, h, false);
    __syncthreads();                                   // B6 (also fences mm4's buf0 reads)
    {
      const int NFRAG = (wn==0) ? 4 : 3;     // 13 N-frags split 4/3/3/3
      f32x4 pacc[16];
      #pragma unroll
      for (int i=0;i<16;++i){ f32x4 z={0.f,0.f,0.f,0.f}; pacc[i]=z; }
      const int abase = lr*TSTRIDE;
      #pragma unroll
      for (int ks=0; ks<8; ++ks){
        bf16x8 a[4];
        #pragma unroll
        for (int mi=0;mi<4;++mi)
          a[mi] = *(const bf16x8*)(buf1 + abase + mi*16*TSTRIDE + ks*32 + lg*8);
        __builtin_amdgcn_s_setprio(1);
        #pragma unroll
        for (int t=0;t<4;++t){
          if (t < NFRAG){
            const int nf = wn + 4*t;
            bf16x8 w = wfp8[li*6656 + ks*832 + lg*208 + nf*16 + lr];
            #pragma unroll
            for (int mi=0;mi<4;++mi)
              pacc[mi*4+t] = mfma16(w, a[mi], pacc[mi*4+t]);
          }
        }
        __builtin_amdgcn_s_setprio(0);
      }
      // p-writes to buf0: its last readers (mm4) were fenced by B6
      #pragma unroll
      for (int t=0;t<4;++t){
        if (t < NFRAG){
          const int nf = wn + 4*t;
          const int col = nf*16 + lg*4;
          f32x4 bv = *(const f32x4*)(bfp + li*PCOLS + col);
          #pragma unroll
          for (int mi=0;mi<4;++mi){
            const int prow = mi*16 + lr;
            u16x4 pk;
            #pragma unroll
            for (int r=0;r<4;++r) pk[r] = f2bf(pacc[mi*4+t][r] + bv[r]);
            *(u16x4*)(buf0 + prow*PSTRIDE + col) = pk;
          }
        }
      }
    }
    __syncthreads();                                   // B7

    // ---- RQ spline on the 8 transformed features (p in buf0) ----
    {
      #pragma unroll
      for (int e=0; e<2; ++e){
        const int fslot = sq*2 + e;
        const int ft = fslot*2 + (li & 1);
        const float xv = x_lds[srow*FDIM + ft];
        const u16* pp = buf0 + srow*PSTRIDE + fslot*26;
        float uw[8], uh[8], us[9];
        #pragma unroll
        for (int k2=0;k2<4;++k2){ u16x2 v = *(const u16x2*)(pp + 2*k2);      uw[2*k2]=bf2f(v[0]); uw[2*k2+1]=bf2f(v[1]); }
        #pragma unroll
        for (int k2=0;k2<4;++k2){ u16x2 v = *(const u16x2*)(pp + 8 + 2*k2);  uh[2*k2]=bf2f(v[0]); uh[2*k2+1]=bf2f(v[1]); }
        #pragma unroll
        for (int k2=0;k2<4;++k2){ u16x2 v = *(const u16x2*)(pp + 16 + 2*k2); us[2*k2]=bf2f(v[0]); us[2*k2+1]=bf2f(v[1]); }
        us[8] = bf2f(pp[24]);
        float mw = uw[0], mh = uh[0];
        #pragma unroll
        for (int k=1;k<8;++k){ mw=fmaxf(mw,uw[k]); mh=fmaxf(mh,uh[k]); }
        float sw=0.f, sh=0.f, bw[8], bh[8];
        #pragma unroll
        for (int k=0;k<8;++k){ bw[k]=__expf(uw[k]-mw); sw+=bw[k]; bh[k]=__expf(uh[k]-mh); sh+=bh[k]; }
        const float wscl = 9.9992f / sw;
        const float hscl = 9.9992f / sh;
        #pragma unroll
        for (int k=0;k<8;++k){ bw[k]=bw[k]*wscl + 1e-4f; bh[k]=bh[k]*hscl + 1e-4f; }
        float dv[9];
        #pragma unroll
        for (int k=0;k<9;++k){
          const float v = us[k] + 0.5411667f;          // log(expm1(1-1e-4))
          const float spv = (v > 15.f) ? v : __logf(1.f + __expf(v));
          dv[k] = spv + 1e-4f;
        }
        const float xr = xv + 5.f;
        float cw=0.f, ch=0.f;
        float x0=0.f, y0=0.f, x1=0.f, y1=0.f, d0=0.f, d1=0.f;
        #pragma unroll
        for (int k=0;k<8;++k){
          const float nw = cw + bw[k];
          const float nh = ch + bh[k];
          const bool take = (k==0) || (xr >= cw);
          if (take){ x0=cw; y0=ch; x1=nw; y1=nh; d0=dv[k]; d1=dv[k+1]; }
          cw = nw; ch = nh;
        }
        const float dx = x1 - x0;
        const float s  = (y1 - y0) / dx;
        float z = (xr - x0) / dx;
        z = fminf(fmaxf(z, 0.f), 1.f);
        const float zm  = 1.f - z;
        const float den = s + (d1 + d0 - 2.f*s)*z*zm;
        const float yout = (y0 - 5.f) + (y1 - y0)*(s*z*z + d0*z*zm)/den;
        const float nrm  = d1*z*z + 2.f*s*z*zm + d0*zm*zm;
        const float ld   = __logf(s*s*nrm/(den*den));
        const bool inside = (xv >= -5.f) && (xv <= 5.f);
        x_lds[srow*FDIM + ft] = inside ? yout : xv;   // own-row write (intra-wave)
        ld_acc += inside ? ld : 0.f;
      }
    }
    // no barrier: next layer's permute/xm touch x (intra-wave) and buf1 (fenced by B7)
    tb ^= 1;
  }

  // ---- base log-prob + reduce 4 threads/row ----
  {
    float s2 = 0.f;
    #pragma unroll
    for (int j=0;j<4;++j){
      const float xv = x_lds[srow*FDIM + sq*4 + j];
      s2 += xv*xv;
    }
    float tot = ld_acc - 0.5f*s2;
    tot += __shfl_xor(tot, 1);
    tot += __shfl_xor(tot, 2);
    if (sq == 0){
      const float sumlogsc = bfp[NLAYER*PCOLS - 1];
      outg[rowg0 + srow] = tot + sumlogsc - 14.70301653127476f;  // 0.5*16*log(2*pi)
    }
  }
}

extern "C" void kernel_launch(void* const* d_in, const int* in_sizes, int n_in,
                              void* d_out, int out_size, void* d_ws, size_t ws_size,
                              hipStream_t stream) {
  (void)in_sizes; (void)n_in; (void)out_size; (void)ws_size;
  const float* x  = (const float*)d_in[0];
  const float* W0 = (const float*)d_in[1];
  const float* b0 = (const float*)d_in[2];
  const float* Wr = (const float*)d_in[3];
  const float* br = (const float*)d_in[4];
  const float* Wf = (const float*)d_in[5];
  const float* bf = (const float*)d_in[6];
  const float* sc = (const float*)d_in[7];
  const float* sh = (const float*)d_in[8];
  const int*   pm = (const int*)d_in[9];

  char* ws = (char*)d_ws;
  u16*   Wrp = (u16*)(ws + WRP_OFF);
  u16*   W0p = (u16*)(ws + W0P_OFF);
  u16*   Wfp = (u16*)(ws + WFP_OFF);
  float* bfp = (float*)(ws + BFP_OFF);

  pack_wr_k<<<1024, 256, 0, stream>>>(Wr, Wrp);
  pack_w0_k<<<32,   256, 0, stream>>>(W0, W0p);
  pack_wf_k<<<208,  256, 0, stream>>>(Wf, Wfp);
  pack_bf_k<<<7,    256, 0, stream>>>(bf, sc, bfp);

  flow_kernel<<<NBATCH/MTILE, NTHREADS, 0, stream>>>(
      x, b0, br, sc, sh, pm, W0p, Wrp, Wfp, bfp, (float*)d_out);
}